// Round 1
// baseline (1930.741 us; speedup 1.0000x reference)
//
#include <hip/hip_runtime.h>
#include <math.h>

#define NN 100000
#define NE 1600000
#define NG 1024
#define HID 128
#define FIN 38
#define MAXDEG 64
#define EPSB 1e-5f

#define BM 64
#define BN 128
#define KC 32

static __device__ __forceinline__ float sigmoidf_(float x){ return 1.f/(1.f+__expf(-x)); }

__global__ void k_degrees(const int* __restrict__ src, const int* __restrict__ dst,
                          int* __restrict__ degO, int* __restrict__ degI){
  int e = blockIdx.x*256 + threadIdx.x;
  if (e < NE){
    atomicAdd(&degO[src[e]], 1);
    atomicAdd(&degI[dst[e]], 1);
  }
}

__global__ void k_norms(const int* __restrict__ degO, const int* __restrict__ degI,
                        float* __restrict__ ns, float* __restrict__ nd){
  int v = blockIdx.x*256 + threadIdx.x;
  if (v < NN){
    ns[v] = rsqrtf(fmaxf((float)degO[v], 1.f));
    nd[v] = rsqrtf(fmaxf((float)degI[v], 1.f));
  }
}

__global__ void k_fill(const int* __restrict__ src, const int* __restrict__ dst,
                       int* __restrict__ cnt, int* __restrict__ eidx){
  int e = blockIdx.x*256 + threadIdx.x;
  if (e < NE){
    int d = dst[e];
    int p = atomicAdd(&cnt[d], 1);
    if (p < MAXDEG) eidx[d*MAXDEG + p] = src[e];
  }
}

// wave-per-node SpMM: out[v] = nd[v] * sum_{e in in(v)} x[src_e] * ns[src_e]
template<int F>
__global__ void k_spmm(const float* __restrict__ x, const int* __restrict__ eidx,
                       const int* __restrict__ degI, const float* __restrict__ ns,
                       const float* __restrict__ nd, float* __restrict__ out){
  int v = (blockIdx.x*256 + threadIdx.x) >> 6;
  int lane = threadIdx.x & 63;
  if (v >= NN) return;
  int deg = degI[v]; if (deg > MAXDEG) deg = MAXDEG;
  const int* row = eidx + v*MAXDEG;
  float ndv = nd[v];
  if constexpr (F == 128){
    float a0=0.f, a1=0.f;
    for (int e=0;e<deg;e++){
      int s = row[e];
      float wv = ns[s];
      const float* xr = x + (size_t)s*128;
      a0 = fmaf(xr[lane], wv, a0);
      a1 = fmaf(xr[lane+64], wv, a1);
    }
    out[(size_t)v*128 + lane] = a0*ndv;
    out[(size_t)v*128 + 64 + lane] = a1*ndv;
  } else {
    float a0=0.f;
    for (int e=0;e<deg;e++){
      int s = row[e];
      float wv = ns[s];
      if (lane < F) a0 = fmaf(x[(size_t)s*F + lane], wv, a0);
    }
    if (lane < F) out[(size_t)v*F + lane] = a0*ndv;
  }
}

// C[M x Nc] = A[M x K] @ W[K x Nc] + bias ; act: 0=raw, 1=sigmoid
// if stats != nullptr: accumulate per-column sum (stats[0..Nc)) and sumsq (stats[Nc..2Nc))
__global__ __launch_bounds__(256)
void k_gemm(const float* __restrict__ A, const float* __restrict__ W,
            const float* __restrict__ bias, float* __restrict__ C,
            int M, int K, int Nc, int act, float* __restrict__ stats){
  __shared__ __align__(16) float At[KC][BM+4];   // transposed A tile (stride 68 -> 16B aligned rows)
  __shared__ __align__(16) float Wt[KC][BN];
  __shared__ float sred[2][BN];
  int m0 = blockIdx.x*BM, n0 = blockIdx.y*BN;
  int t = threadIdx.x;
  int tx = t & 15, ty = t >> 4;
  float acc[4][8] = {};
  for (int k0=0;k0<K;k0+=KC){
    for (int i=t;i<BM*KC;i+=256){
      int m = i>>5, kk = i&31;
      int gm = m0+m, gk = k0+kk;
      At[kk][m] = (gm<M && gk<K) ? A[(size_t)gm*K+gk] : 0.f;
    }
    for (int i=t;i<KC*BN;i+=256){
      int kk = i>>7, c = i&127;
      int gk = k0+kk, gc = n0+c;
      Wt[kk][c] = (gk<K && gc<Nc) ? W[(size_t)gk*Nc+gc] : 0.f;
    }
    __syncthreads();
    #pragma unroll 8
    for (int kk=0;kk<KC;kk++){
      float4 a4 = *(const float4*)&At[kk][ty*4];
      float4 w0 = *(const float4*)&Wt[kk][tx*8];
      float4 w1 = *(const float4*)&Wt[kk][tx*8+4];
      float a[4] = {a4.x,a4.y,a4.z,a4.w};
      float wv[8] = {w0.x,w0.y,w0.z,w0.w,w1.x,w1.y,w1.z,w1.w};
      #pragma unroll
      for (int i=0;i<4;i++)
        #pragma unroll
        for (int j=0;j<8;j++)
          acc[i][j] = fmaf(a[i], wv[j], acc[i][j]);
    }
    __syncthreads();
  }
  float csum[8] = {}, csq[8] = {};
  #pragma unroll
  for (int i=0;i<4;i++){
    int gm = m0 + ty*4 + i;
    if (gm >= M) continue;
    #pragma unroll
    for (int j=0;j<8;j++){
      int gc = n0 + tx*8 + j;
      if (gc >= Nc) continue;
      float v = acc[i][j] + bias[gc];
      if (act == 1) v = sigmoidf_(v);
      C[(size_t)gm*Nc + gc] = v;
      csum[j] += v; csq[j] += v*v;
    }
  }
  if (stats){
    ((float*)sred)[t] = 0.f;          // 256 = 2*BN entries
    __syncthreads();
    #pragma unroll
    for (int j=0;j<8;j++){
      atomicAdd(&sred[0][tx*8+j], csum[j]);
      atomicAdd(&sred[1][tx*8+j], csq[j]);
    }
    __syncthreads();
    if (t < BN){
      int gc = n0 + t;
      if (gc < Nc){
        atomicAdd(&stats[gc], sred[0][t]);
        atomicAdd(&stats[Nc + gc], sred[1][t]);
      }
    }
  }
}

__global__ void k_bnfin(const float* __restrict__ stats, const float* __restrict__ g,
                        const float* __restrict__ be, float invM, int C,
                        float* __restrict__ scale, float* __restrict__ shift){
  int c = blockIdx.x*blockDim.x + threadIdx.x;
  if (c < C){
    float m = stats[c]*invM;
    float var = fmaxf(stats[C+c]*invM - m*m, 0.f);
    float inv = rsqrtf(var + EPSB);
    float sc = g[c]*inv;
    scale[c] = sc;
    shift[c] = fmaf(-sc, m, be[c]);
  }
}

__global__ void k_bnapply(float* __restrict__ X, const float* __restrict__ scale,
                          const float* __restrict__ shift, size_t total, int cmask){
  size_t i = (size_t)blockIdx.x*blockDim.x + threadIdx.x;
  size_t stride = (size_t)gridDim.x*blockDim.x;
  for (; i < total; i += stride){
    int c = (int)(i & (size_t)cmask);
    X[i] = fmaxf(fmaf(X[i], scale[c], shift[c]), 0.f);
  }
}

__global__ void k_atomw(const float* __restrict__ x, const float* __restrict__ aw,
                        const float* __restrict__ ab, float* __restrict__ awout,
                        float* __restrict__ wsig){
  int v = (blockIdx.x*256 + threadIdx.x) >> 6;
  int lane = threadIdx.x & 63;
  if (v >= NN) return;
  const float* xr = x + (size_t)v*128;
  float s = xr[lane]*aw[lane] + xr[lane+64]*aw[lane+64];
  #pragma unroll
  for (int o=32;o>0;o>>=1) s += __shfl_xor(s, o);
  if (lane == 0){
    float tv = s + ab[0];
    awout[v] = tv;
    wsig[v] = sigmoidf_(tv);
  }
}

__global__ void k_bounds(const int* __restrict__ n2g, int* __restrict__ gs, int* __restrict__ ge){
  int v = blockIdx.x*256 + threadIdx.x;
  if (v < NN){
    int g = n2g[v];
    atomicMin(&gs[g], v);
    atomicMax(&ge[g], v+1);
  }
}

__global__ void k_readout(const float* __restrict__ x, const float* __restrict__ wsig,
                          const int* __restrict__ gs, const int* __restrict__ ge,
                          float* __restrict__ hg){
  int g = (blockIdx.x*256 + threadIdx.x) >> 6;
  int lane = threadIdx.x & 63;
  if (g >= NG) return;
  int s = gs[g], e = ge[g];
  float a0=0.f, a1=0.f;
  for (int n=s; n<e; n++){
    float wn = wsig[n];
    a0 = fmaf(x[(size_t)n*128+lane], wn, a0);
    a1 = fmaf(x[(size_t)n*128+64+lane], wn, a1);
  }
  hg[(size_t)g*128+lane]=a0;
  hg[(size_t)g*128+64+lane]=a1;
}

extern "C" void kernel_launch(void* const* d_in, const int* in_sizes, int n_in,
                              void* d_out, int out_size, void* d_ws, size_t ws_size,
                              hipStream_t stream){
  const float* h   = (const float*)d_in[0];
  const int*   src = (const int*)d_in[1];
  const int*   dst = (const int*)d_in[2];
  const int*   n2g = (const int*)d_in[3];
  const float* W1  = (const float*)d_in[4];
  const float* b1  = (const float*)d_in[5];
  const float* g1  = (const float*)d_in[6];
  const float* be1 = (const float*)d_in[7];
  const float* W2s = (const float*)d_in[8];
  const float* b2s = (const float*)d_in[9];
  const float* g2s = (const float*)d_in[10];
  const float* be2s= (const float*)d_in[11];
  const float* aw  = (const float*)d_in[12];
  const float* ab  = (const float*)d_in[13];
  const float* Wf1 = (const float*)d_in[14];
  const float* bf1 = (const float*)d_in[15];
  const float* gf1 = (const float*)d_in[16];
  const float* bef1= (const float*)d_in[17];
  const float* Wl  = (const float*)d_in[18];
  const float* bl  = (const float*)d_in[19];
  const float* gl  = (const float*)d_in[20];
  const float* bel = (const float*)d_in[21];
  const float* Wf2 = (const float*)d_in[22];
  const float* bf2 = (const float*)d_in[23];
  float* out = (float*)d_out;

  char* p = (char*)d_ws;
  auto carve = [&](size_t bytes)->void*{
    void* r = (void*)p; p += (bytes + 255) & ~(size_t)255; return r;
  };
  float* xA   = (float*)carve((size_t)NN*128*4);
  float* xB   = (float*)carve((size_t)NN*128*4);
  int*   eidx = (int*)carve((size_t)NN*MAXDEG*4);
  int*   degO = (int*)carve((size_t)NN*4);
  int*   degI = (int*)carve((size_t)NN*4);
  int*   cnt  = (int*)carve((size_t)NN*4);
  float* ns   = (float*)carve((size_t)NN*4);
  float* nd   = (float*)carve((size_t)NN*4);
  float* wsig = (float*)carve((size_t)NN*4);
  int*   gs   = (int*)carve((size_t)NG*4);
  int*   ge   = (int*)carve((size_t)NG*4);
  float* hg   = (float*)carve((size_t)NG*128*4);
  float* y1   = (float*)carve((size_t)NG*512*4);
  float* y2   = (float*)carve((size_t)NG*256*4);
  float* stats= (float*)carve(4096*4);
  float* scale= (float*)carve(512*4);
  float* shift= (float*)carve(512*4);

  float* st1  = stats;           // 2*128
  float* st2a = stats + 256;
  float* st2b = stats + 512;
  float* st2c = stats + 768;
  float* stf1 = stats + 1024;    // 2*512
  float* stl  = stats + 2048;    // 2*256
  float* st2[3] = { st2a, st2b, st2c };

  hipMemsetAsync(degO, 0, (size_t)NN*4, stream);
  hipMemsetAsync(degI, 0, (size_t)NN*4, stream);
  hipMemsetAsync(cnt,  0, (size_t)NN*4, stream);
  hipMemsetAsync(stats,0, (size_t)4096*4, stream);
  hipMemsetAsync(gs, 0x7F, (size_t)NG*4, stream);
  hipMemsetAsync(ge, 0,    (size_t)NG*4, stream);

  k_degrees<<<(NE+255)/256, 256, 0, stream>>>(src, dst, degO, degI);
  k_norms  <<<(NN+255)/256, 256, 0, stream>>>(degO, degI, ns, nd);
  k_fill   <<<(NE+255)/256, 256, 0, stream>>>(src, dst, cnt, eidx);

  const int nodeBlocks = (NN + 3)/4;   // 4 waves per 256-thread block

  // layer 1: F_IN=38 -> 128
  k_spmm<38><<<nodeBlocks, 256, 0, stream>>>(h, eidx, degI, ns, nd, xB);
  k_gemm<<<dim3((NN+BM-1)/BM, 1), 256, 0, stream>>>(xB, W1, b1, xA, NN, 38, 128, 0, st1);
  k_bnfin<<<1, 128, 0, stream>>>(st1, g1, be1, 1.0f/(float)NN, 128, scale, shift);
  k_bnapply<<<2048, 256, 0, stream>>>(xA, scale, shift, (size_t)NN*128, 127);

  // layers 2..4: 128 -> 128
  for (int i=0;i<3;i++){
    k_spmm<128><<<nodeBlocks, 256, 0, stream>>>(xA, eidx, degI, ns, nd, xB);
    k_gemm<<<dim3((NN+BM-1)/BM, 1), 256, 0, stream>>>(xB, W2s + (size_t)i*128*128, b2s + i*128,
                                                      xA, NN, 128, 128, 0, st2[i]);
    k_bnfin<<<1, 128, 0, stream>>>(st2[i], g2s + i*128, be2s + i*128, 1.0f/(float)NN, 128, scale, shift);
    k_bnapply<<<2048, 256, 0, stream>>>(xA, scale, shift, (size_t)NN*128, 127);
  }

  // readout
  k_atomw<<<nodeBlocks, 256, 0, stream>>>(xA, aw, ab, out + (size_t)NG*67, wsig);
  k_bounds<<<(NN+255)/256, 256, 0, stream>>>(n2g, gs, ge);
  k_readout<<<NG/4, 256, 0, stream>>>(xA, wsig, gs, ge, hg);

  // MLP head
  k_gemm<<<dim3(NG/BM, 4), 256, 0, stream>>>(hg, Wf1, bf1, y1, NG, 128, 512, 0, stf1);
  k_bnfin<<<1, 512, 0, stream>>>(stf1, gf1, bef1, 1.0f/(float)NG, 512, scale, shift);
  k_bnapply<<<512, 256, 0, stream>>>(y1, scale, shift, (size_t)NG*512, 511);

  k_gemm<<<dim3(NG/BM, 2), 256, 0, stream>>>(y1, Wl, bl, y2, NG, 512, 256, 0, stl);
  k_bnfin<<<1, 256, 0, stream>>>(stl, gl, bel, 1.0f/(float)NG, 256, scale, shift);
  k_bnapply<<<256, 256, 0, stream>>>(y2, scale, shift, (size_t)NG*256, 255);

  k_gemm<<<dim3(NG/BM, 1), 256, 0, stream>>>(y2, Wf2, bf2, out, NG, 256, 67, 1, nullptr);
}

// Round 2
// 1334.944 us; speedup vs baseline: 1.4463x; 1.4463x over previous
//
#include <hip/hip_runtime.h>
#include <math.h>

#define NN 100000
#define NE 1600000
#define NG 1024
#define MAXDEG 64
#define EPSB 1e-5f

typedef __attribute__((ext_vector_type(4))) float f32x4;
typedef __attribute__((ext_vector_type(8))) short bf16x8;

static __device__ __forceinline__ float sigmoidf_(float x){ return 1.f/(1.f+__expf(-x)); }
static __device__ __forceinline__ float bf2f(unsigned short u){
  union{unsigned int i; float f;} x; x.i = ((unsigned int)u)<<16; return x.f;
}
static __device__ __forceinline__ unsigned short f2bf(float f){
  union{float f; unsigned int i;} x; x.f = f;
  unsigned int r = x.i + 0x7fffu + ((x.i>>16)&1u);
  return (unsigned short)(r>>16);
}
static __device__ __forceinline__ unsigned int pack2(float a, float b){
  return (unsigned int)f2bf(a) | ((unsigned int)f2bf(b)<<16);
}

// ---------------- graph prep ----------------
__global__ void k_degrees(const int* __restrict__ src, const int* __restrict__ dst,
                          int* __restrict__ degO, int* __restrict__ degI){
  int e = blockIdx.x*256 + threadIdx.x;
  if (e < NE){ atomicAdd(&degO[src[e]], 1); atomicAdd(&degI[dst[e]], 1); }
}

__global__ void k_norms(const int* __restrict__ degO, const int* __restrict__ degI,
                        float* __restrict__ ns, float* __restrict__ nd){
  int v = blockIdx.x*256 + threadIdx.x;
  if (v < NN){
    ns[v] = rsqrtf(fmaxf((float)degO[v], 1.f));
    nd[v] = rsqrtf(fmaxf((float)degI[v], 1.f));
  }
}

__global__ void k_fill(const int* __restrict__ src, const int* __restrict__ dst,
                       int* __restrict__ cnt, int* __restrict__ eidx){
  int e = blockIdx.x*256 + threadIdx.x;
  if (e < NE){
    int d = dst[e];
    int p = atomicAdd(&cnt[d], 1);
    if (p < MAXDEG) eidx[d*MAXDEG + p] = src[e];
  }
}

// ---------------- weight convert: W fp32 [K][Nc] -> Wt bf16 [Nc][Kpad], zero-pad k>=K
__global__ void k_convW(const float* __restrict__ W, unsigned short* __restrict__ Wt,
                        int K, int Nc, int Kpad){
  int i = blockIdx.x*256 + threadIdx.x;
  if (i >= Nc*Kpad) return;
  int c = i / Kpad, k = i % Kpad;
  Wt[i] = (k < K) ? f2bf(W[(size_t)k*Nc + c]) : (unsigned short)0;
}

// ---------------- SpMM layer 1: h fp32 [N][38] -> agg bf16 [N][64] (cols 38+ zero), *ns[src]*nd[v]
__global__ void k_spmm1(const float* __restrict__ h, const int* __restrict__ eidx,
                        const int* __restrict__ degI, const float* __restrict__ ns,
                        const float* __restrict__ nd, unsigned short* __restrict__ agg){
  int v = (blockIdx.x*256 + threadIdx.x) >> 6;
  int lane = threadIdx.x & 63;
  if (v >= NN) return;
  int deg = degI[v]; if (deg > MAXDEG) deg = MAXDEG;
  const int* row = eidx + v*MAXDEG;
  float a0 = 0.f;
  for (int e=0;e<deg;e++){
    int s = row[e];
    float wv = ns[s];
    if (lane < 38) a0 = fmaf(h[(size_t)s*38 + lane], wv, a0);
  }
  agg[(size_t)v*64 + lane] = (lane < 38) ? f2bf(a0*nd[v]) : (unsigned short)0;
}

// ---------------- SpMM layers 2..4: xpre bf16 [N][128], fold BN(scale,shift)+ReLU, *ns*nd -> agg bf16
__global__ void k_spmmH(const unsigned short* __restrict__ xpre, const int* __restrict__ eidx,
                        const int* __restrict__ degI, const float* __restrict__ ns,
                        const float* __restrict__ nd, const float* __restrict__ scale,
                        const float* __restrict__ shift, unsigned short* __restrict__ agg){
  int v = (blockIdx.x*256 + threadIdx.x) >> 6;
  int lane = threadIdx.x & 63;
  if (v >= NN) return;
  int deg = degI[v]; if (deg > MAXDEG) deg = MAXDEG;
  const int* row = eidx + v*MAXDEG;
  int c0 = 2*lane;
  float sc0 = scale[c0], sc1 = scale[c0+1];
  float sh0 = shift[c0], sh1 = shift[c0+1];
  float a0 = 0.f, a1 = 0.f;
  for (int e=0;e<deg;e++){
    int s = row[e];
    float wv = ns[s];
    unsigned int u = *(const unsigned int*)(xpre + (size_t)s*128 + c0);
    float x0 = fmaxf(fmaf(bf2f((unsigned short)(u & 0xffff)), sc0, sh0), 0.f);
    float x1 = fmaxf(fmaf(bf2f((unsigned short)(u >> 16)),   sc1, sh1), 0.f);
    a0 = fmaf(x0, wv, a0);
    a1 = fmaf(x1, wv, a1);
  }
  float ndv = nd[v];
  *(unsigned int*)(agg + (size_t)v*128 + c0) = pack2(a0*ndv, a1*ndv);
}

// ---------------- MFMA GEMM: C = A[M][K]bf16 @ Wt[Nc][K]bf16^T + bias, out bf16, fused BN stats
// tile 128x128, 256 thr (4 waves 2x2 of 64x64), BK=64, K % 64 == 0
__global__ __launch_bounds__(256)
void k_mgemm(const unsigned short* __restrict__ A, const unsigned short* __restrict__ Wt,
             const float* __restrict__ bias, unsigned short* __restrict__ Cout,
             float* __restrict__ stats, int M, int K, int Nc){
  __shared__ unsigned short As[128][72];
  __shared__ unsigned short Bs[128][72];
  __shared__ float sred[2][128];
  int m0 = blockIdx.x*128, n0 = blockIdx.y*128;
  int t = threadIdx.x, w = t>>6, lane = t&63;
  int wr = (w>>1)*64, wc = (w&1)*64;
  f32x4 acc[4][4] = {};

  int ar = t>>3;          // 0..31
  int ac = (t&7)*8;       // 0..56 step 8
  for (int k0=0; k0<K; k0+=64){
    #pragma unroll
    for (int rr=0; rr<128; rr+=32){
      int gm = m0 + ar + rr;
      bf16x8 val = {};
      if (gm < M) val = *(const bf16x8*)(A + (size_t)gm*K + k0 + ac);
      *(bf16x8*)&As[ar+rr][ac] = val;
    }
    #pragma unroll
    for (int rr=0; rr<128; rr+=32){
      int gc = n0 + ar + rr;
      bf16x8 val = {};
      if (gc < Nc) val = *(const bf16x8*)(Wt + (size_t)gc*K + k0 + ac);
      *(bf16x8*)&Bs[ar+rr][ac] = val;
    }
    __syncthreads();
    int rsel = lane & 15;
    #pragma unroll
    for (int kk=0; kk<64; kk+=32){
      int ksel = kk + (lane>>4)*8;
      bf16x8 af[4], bfr[4];
      #pragma unroll
      for (int i=0;i<4;i++) af[i]  = *(const bf16x8*)&As[wr + i*16 + rsel][ksel];
      #pragma unroll
      for (int j=0;j<4;j++) bfr[j] = *(const bf16x8*)&Bs[wc + j*16 + rsel][ksel];
      #pragma unroll
      for (int i=0;i<4;i++)
        #pragma unroll
        for (int j=0;j<4;j++)
          acc[i][j] = __builtin_amdgcn_mfma_f32_16x16x32_bf16(af[i], bfr[j], acc[i][j], 0, 0, 0);
    }
    __syncthreads();
  }

  // epilogue: D row = wr+i*16+(lane>>4)*4+r, col = wc+j*16+(lane&15)
  float csum[4] = {}, csq[4] = {};
  int colsel = lane & 15, rowsel = (lane>>4)*4;
  #pragma unroll
  for (int j=0;j<4;j++){
    int gc = n0 + wc + j*16 + colsel;
    float bv = (gc < Nc) ? bias[gc] : 0.f;
    #pragma unroll
    for (int i=0;i<4;i++){
      #pragma unroll
      for (int r=0;r<4;r++){
        int gm = m0 + wr + i*16 + rowsel + r;
        if (gm < M && gc < Nc){
          float v = acc[i][j][r] + bv;
          Cout[(size_t)gm*Nc + gc] = f2bf(v);
          csum[j] += v; csq[j] += v*v;
        }
      }
    }
  }
  if (stats){
    ((float*)sred)[t] = 0.f;
    __syncthreads();
    #pragma unroll
    for (int j=0;j<4;j++){
      int lc = wc + j*16 + colsel;
      atomicAdd(&sred[0][lc], csum[j]);
      atomicAdd(&sred[1][lc], csq[j]);
    }
    __syncthreads();
    if (t < 128){
      int gc = n0 + t;
      if (gc < Nc){
        atomicAdd(&stats[gc],      sred[0][t]);
        atomicAdd(&stats[Nc + gc], sred[1][t]);
      }
    }
  }
}

// ---------------- BN finalize -> scale/shift
__global__ void k_bnfin(const float* __restrict__ stats, const float* __restrict__ g,
                        const float* __restrict__ be, float invM, int C,
                        float* __restrict__ scale, float* __restrict__ shift){
  int c = blockIdx.x*blockDim.x + threadIdx.x;
  if (c < C){
    float m = stats[c]*invM;
    float var = fmaxf(stats[C+c]*invM - m*m, 0.f);
    float inv = rsqrtf(var + EPSB);
    float sc = g[c]*inv;
    scale[c] = sc;
    shift[c] = fmaf(-sc, m, be[c]);
  }
}

// ---------------- BN apply + ReLU on bf16 pairs
__global__ void k_bnapply_bf(const unsigned int* __restrict__ X, unsigned int* __restrict__ Y,
                             const float* __restrict__ scale, const float* __restrict__ shift,
                             size_t totalPairs, int pairMask){
  size_t i = (size_t)blockIdx.x*blockDim.x + threadIdx.x;
  size_t stride = (size_t)gridDim.x*blockDim.x;
  for (; i < totalPairs; i += stride){
    int c0 = 2*(int)(i & (size_t)pairMask);
    unsigned int u = X[i];
    float x0 = fmaxf(fmaf(bf2f((unsigned short)(u & 0xffff)), scale[c0],   shift[c0]),   0.f);
    float x1 = fmaxf(fmaf(bf2f((unsigned short)(u >> 16)),    scale[c0+1], shift[c0+1]), 0.f);
    Y[i] = pack2(x0, x1);
  }
}

// ---------------- readout ----------------
__global__ void k_atomw(const unsigned short* __restrict__ x, const float* __restrict__ aw,
                        const float* __restrict__ ab, float* __restrict__ awout,
                        float* __restrict__ wsig){
  int v = (blockIdx.x*256 + threadIdx.x) >> 6;
  int lane = threadIdx.x & 63;
  if (v >= NN) return;
  unsigned int u = *(const unsigned int*)(x + (size_t)v*128 + 2*lane);
  float s = bf2f((unsigned short)(u & 0xffff))*aw[2*lane]
          + bf2f((unsigned short)(u >> 16))*aw[2*lane+1];
  #pragma unroll
  for (int o=32;o>0;o>>=1) s += __shfl_xor(s, o);
  if (lane == 0){
    float tv = s + ab[0];
    awout[v] = tv;
    wsig[v] = sigmoidf_(tv);
  }
}

__global__ void k_bounds(const int* __restrict__ n2g, int* __restrict__ gs, int* __restrict__ ge){
  int v = blockIdx.x*256 + threadIdx.x;
  if (v < NN){
    int g = n2g[v];
    atomicMin(&gs[g], v);
    atomicMax(&ge[g], v+1);
  }
}

__global__ void k_readout(const unsigned short* __restrict__ x, const float* __restrict__ wsig,
                          const int* __restrict__ gs, const int* __restrict__ ge,
                          unsigned short* __restrict__ hg){
  int g = (blockIdx.x*256 + threadIdx.x) >> 6;
  int lane = threadIdx.x & 63;
  if (g >= NG) return;
  int s = gs[g], e = ge[g];
  float a0=0.f, a1=0.f;
  for (int n=s; n<e; n++){
    float wn = wsig[n];
    unsigned int u = *(const unsigned int*)(x + (size_t)n*128 + 2*lane);
    a0 = fmaf(bf2f((unsigned short)(u & 0xffff)), wn, a0);
    a1 = fmaf(bf2f((unsigned short)(u >> 16)),    wn, a1);
  }
  *(unsigned int*)(hg + (size_t)g*128 + 2*lane) = pack2(a0, a1);
}

// ---------------- final small GEMM + sigmoid: y2 bf16 [1024][256] @ Wf2 fp32 [256][67]
__global__ void k_final(const unsigned short* __restrict__ y2, const float* __restrict__ Wf2,
                        const float* __restrict__ bf2v, float* __restrict__ out){
  int idx = blockIdx.x*256 + threadIdx.x;
  if (idx >= NG*67) return;
  int g = idx / 67, c = idx % 67;
  float s = bf2v[c];
  const unsigned short* row = y2 + (size_t)g*256;
  for (int k=0;k<256;k+=2){
    unsigned int u = *(const unsigned int*)(row + k);
    s = fmaf(bf2f((unsigned short)(u & 0xffff)), Wf2[(size_t)k*67 + c], s);
    s = fmaf(bf2f((unsigned short)(u >> 16)),    Wf2[(size_t)(k+1)*67 + c], s);
  }
  out[(size_t)g*67 + c] = sigmoidf_(s);
}

extern "C" void kernel_launch(void* const* d_in, const int* in_sizes, int n_in,
                              void* d_out, int out_size, void* d_ws, size_t ws_size,
                              hipStream_t stream){
  const float* h   = (const float*)d_in[0];
  const int*   src = (const int*)d_in[1];
  const int*   dst = (const int*)d_in[2];
  const int*   n2g = (const int*)d_in[3];
  const float* W1  = (const float*)d_in[4];
  const float* b1  = (const float*)d_in[5];
  const float* g1  = (const float*)d_in[6];
  const float* be1 = (const float*)d_in[7];
  const float* W2s = (const float*)d_in[8];
  const float* b2s = (const float*)d_in[9];
  const float* g2s = (const float*)d_in[10];
  const float* be2s= (const float*)d_in[11];
  const float* aw  = (const float*)d_in[12];
  const float* ab  = (const float*)d_in[13];
  const float* Wf1 = (const float*)d_in[14];
  const float* bf1 = (const float*)d_in[15];
  const float* gf1 = (const float*)d_in[16];
  const float* bef1= (const float*)d_in[17];
  const float* Wl  = (const float*)d_in[18];
  const float* bl  = (const float*)d_in[19];
  const float* gl  = (const float*)d_in[20];
  const float* bel = (const float*)d_in[21];
  const float* Wf2 = (const float*)d_in[22];
  const float* bf2v= (const float*)d_in[23];
  float* out = (float*)d_out;

  char* p = (char*)d_ws;
  auto carve = [&](size_t bytes)->void*{
    void* r = (void*)p; p += (bytes + 255) & ~(size_t)255; return r;
  };
  unsigned short* X    = (unsigned short*)carve((size_t)NN*128*2); // xpre (pre-BN)
  unsigned short* Ag   = (unsigned short*)carve((size_t)NN*128*2); // agg / later x4
  unsigned short* A38  = (unsigned short*)carve((size_t)NN*64*2);
  int*   eidx = (int*)carve((size_t)NN*MAXDEG*4);
  int*   degO = (int*)carve((size_t)NN*4);
  int*   degI = (int*)carve((size_t)NN*4);
  int*   cnt  = (int*)carve((size_t)NN*4);
  float* ns   = (float*)carve((size_t)NN*4);
  float* nd   = (float*)carve((size_t)NN*4);
  float* wsig = (float*)carve((size_t)NN*4);
  int*   gs   = (int*)carve((size_t)NG*4);
  int*   ge   = (int*)carve((size_t)NG*4);
  unsigned short* hg  = (unsigned short*)carve((size_t)NG*128*2);
  unsigned short* y1p = (unsigned short*)carve((size_t)NG*512*2);
  unsigned short* y1  = (unsigned short*)carve((size_t)NG*512*2);
  unsigned short* y2p = (unsigned short*)carve((size_t)NG*256*2);
  unsigned short* y2  = (unsigned short*)carve((size_t)NG*256*2);
  float* stats= (float*)carve(4096*4);
  float* scale= (float*)carve(512*4);
  float* shift= (float*)carve(512*4);
  unsigned short* W1t  = (unsigned short*)carve((size_t)128*64*2);
  unsigned short* W2t  = (unsigned short*)carve((size_t)3*128*128*2);
  unsigned short* Wf1t = (unsigned short*)carve((size_t)512*128*2);
  unsigned short* Wlt  = (unsigned short*)carve((size_t)256*512*2);

  float* st1  = stats;          // 2*128
  float* st2a = stats + 256;
  float* st2b = stats + 512;
  float* st2c = stats + 768;
  float* stf1 = stats + 1024;   // 2*512
  float* stl  = stats + 2048;   // 2*256
  float* st2[3] = { st2a, st2b, st2c };

  hipMemsetAsync(degO, 0, (size_t)NN*4, stream);
  hipMemsetAsync(degI, 0, (size_t)NN*4, stream);
  hipMemsetAsync(cnt,  0, (size_t)NN*4, stream);
  hipMemsetAsync(stats,0, (size_t)4096*4, stream);
  hipMemsetAsync(gs, 0x7F, (size_t)NG*4, stream);
  hipMemsetAsync(ge, 0,    (size_t)NG*4, stream);

  // graph prep + weight conversion
  k_degrees<<<(NE+255)/256, 256, 0, stream>>>(src, dst, degO, degI);
  k_norms  <<<(NN+255)/256, 256, 0, stream>>>(degO, degI, ns, nd);
  k_fill   <<<(NE+255)/256, 256, 0, stream>>>(src, dst, cnt, eidx);

  k_convW<<<(128*64+255)/256, 256, 0, stream>>>(W1, W1t, 38, 128, 64);
  for (int i=0;i<3;i++)
    k_convW<<<(128*128+255)/256, 256, 0, stream>>>(W2s + (size_t)i*128*128, W2t + (size_t)i*128*128, 128, 128, 128);
  k_convW<<<(512*128+255)/256, 256, 0, stream>>>(Wf1, Wf1t, 128, 512, 128);
  k_convW<<<(256*512+255)/256, 256, 0, stream>>>(Wl, Wlt, 512, 256, 512);

  const int nodeBlocks = (NN + 3)/4;
  const int gemmBlocks = (NN + 127)/128;

  // layer 1
  k_spmm1<<<nodeBlocks, 256, 0, stream>>>(h, eidx, degI, ns, nd, A38);
  k_mgemm<<<dim3(gemmBlocks,1), 256, 0, stream>>>(A38, W1t, b1, X, st1, NN, 64, 128);
  k_bnfin<<<1, 128, 0, stream>>>(st1, g1, be1, 1.0f/(float)NN, 128, scale, shift);

  // layers 2..4 (BN+ReLU folded into the SpMM gather)
  for (int i=0;i<3;i++){
    k_spmmH<<<nodeBlocks, 256, 0, stream>>>(X, eidx, degI, ns, nd, scale, shift, Ag);
    k_mgemm<<<dim3(gemmBlocks,1), 256, 0, stream>>>(Ag, W2t + (size_t)i*128*128, b2s + i*128,
                                                    X, st2[i], NN, 128, 128);
    k_bnfin<<<1, 128, 0, stream>>>(st2[i], g2s + i*128, be2s + i*128, 1.0f/(float)NN, 128, scale, shift);
  }

  // layer-4 activation (Ag reused as x4)
  k_bnapply_bf<<<2048, 256, 0, stream>>>((const unsigned int*)X, (unsigned int*)Ag,
                                         scale, shift, (size_t)NN*64, 63);

  // readout
  k_atomw<<<nodeBlocks, 256, 0, stream>>>(Ag, aw, ab, out + (size_t)NG*67, wsig);
  k_bounds<<<(NN+255)/256, 256, 0, stream>>>(n2g, gs, ge);
  k_readout<<<NG/4, 256, 0, stream>>>(Ag, wsig, gs, ge, hg);

  // head
  k_mgemm<<<dim3(NG/128, 4), 256, 0, stream>>>(hg, Wf1t, bf1, y1p, stf1, NG, 128, 512);
  k_bnfin<<<1, 512, 0, stream>>>(stf1, gf1, bef1, 1.0f/(float)NG, 512, scale, shift);
  k_bnapply_bf<<<512, 256, 0, stream>>>((const unsigned int*)y1p, (unsigned int*)y1,
                                        scale, shift, (size_t)NG*256, 255);

  k_mgemm<<<dim3(NG/128, 2), 256, 0, stream>>>(y1, Wlt, bl, y2p, stl, NG, 512, 256);
  k_bnfin<<<1, 256, 0, stream>>>(stl, gl, bel, 1.0f/(float)NG, 256, scale, shift);
  k_bnapply_bf<<<256, 256, 0, stream>>>((const unsigned int*)y2p, (unsigned int*)y2,
                                        scale, shift, (size_t)NG*128, 127);

  k_final<<<(NG*67+255)/256, 256, 0, stream>>>(y2, Wf2, bf2v, out);
}

// Round 3
// 904.526 us; speedup vs baseline: 2.1345x; 1.4758x over previous
//
#include <hip/hip_runtime.h>
#include <math.h>

#define NN 100000
#define NE 1600000
#define NG 1024
#define MAXDEG 64
#define EPSB 1e-5f

typedef __attribute__((ext_vector_type(4))) float f32x4;
typedef __attribute__((ext_vector_type(8))) short bf16x8;

static __device__ __forceinline__ float sigmoidf_(float x){ return 1.f/(1.f+__expf(-x)); }
static __device__ __forceinline__ float bf2f(unsigned short u){
  union{unsigned int i; float f;} x; x.i = ((unsigned int)u)<<16; return x.f;
}
static __device__ __forceinline__ float lo2f(unsigned int u){
  union{unsigned int i; float f;} x; x.i = u<<16; return x.f;
}
static __device__ __forceinline__ float hi2f(unsigned int u){
  union{unsigned int i; float f;} x; x.i = u & 0xffff0000u; return x.f;
}
static __device__ __forceinline__ unsigned short f2bf(float f){
  union{float f; unsigned int i;} x; x.f = f;
  unsigned int r = x.i + 0x7fffu + ((x.i>>16)&1u);
  return (unsigned short)(r>>16);
}
static __device__ __forceinline__ unsigned int pack2(float a, float b){
  return (unsigned int)f2bf(a) | ((unsigned int)f2bf(b)<<16);
}

// ---------------- graph prep: degrees + CSR fill in one edge pass ----------------
__global__ void k_fillall(const int* __restrict__ src, const int* __restrict__ dst,
                          int* __restrict__ degO, int* __restrict__ cnt, int* __restrict__ eidx){
  int e = blockIdx.x*256 + threadIdx.x;
  if (e < NE){
    int s = src[e], d = dst[e];
    atomicAdd(&degO[s], 1);
    int p = atomicAdd(&cnt[d], 1);
    if (p < MAXDEG) eidx[d*MAXDEG + p] = s;
  }
}

__global__ void k_norms(const int* __restrict__ degO, const int* __restrict__ degI,
                        float* __restrict__ ns, float* __restrict__ nd){
  int v = blockIdx.x*256 + threadIdx.x;
  if (v < NN){
    ns[v] = rsqrtf(fmaxf((float)degO[v], 1.f));
    nd[v] = rsqrtf(fmaxf((float)degI[v], 1.f));
  }
}

// ---------------- weight convert: W fp32 [K][Nc] -> Wt bf16 [Nc][Kpad]
__global__ void k_convW(const float* __restrict__ W, unsigned short* __restrict__ Wt,
                        int K, int Nc, int Kpad){
  int i = blockIdx.x*256 + threadIdx.x;
  if (i >= Nc*Kpad) return;
  int c = i / Kpad, k = i % Kpad;
  Wt[i] = (k < K) ? f2bf(W[(size_t)k*Nc + c]) : (unsigned short)0;
}

// ---------------- layer-1 prep: hn[v][40] fp32 = h[v][c]*ns[v] (pad 0) ----------------
__global__ void k_prep1(const float* __restrict__ h, const float* __restrict__ ns,
                        float* __restrict__ hn){
  int i = blockIdx.x*256 + threadIdx.x;
  if (i >= NN*40) return;
  int v = i / 40, c = i - v*40;
  hn[i] = (c < 38) ? h[(size_t)v*38 + c]*ns[v] : 0.f;
}

// ---------------- layer-1 gather-sum over fp32 [N][40] rows, unroll 4 ----------------
__global__ __launch_bounds__(256)
void k_gs40(const float* __restrict__ hn, const int* __restrict__ eidx,
            const int* __restrict__ degI, const float* __restrict__ nd,
            unsigned short* __restrict__ agg){
  int v = (blockIdx.x*256 + threadIdx.x) >> 6;
  int lane = threadIdx.x & 63;
  if (v >= NN) return;
  int deg = degI[v]; if (deg > MAXDEG) deg = MAXDEG;
  const int* row = eidx + v*MAXDEG;
  float a = 0.f;
  int e = 0;
  for (; e+4 <= deg; e += 4){
    int4 s4 = *(const int4*)(row + e);
    if (lane < 40){
      float x0 = hn[(size_t)s4.x*40 + lane];
      float x1 = hn[(size_t)s4.y*40 + lane];
      float x2 = hn[(size_t)s4.z*40 + lane];
      float x3 = hn[(size_t)s4.w*40 + lane];
      a += x0; a += x1; a += x2; a += x3;
    }
  }
  for (; e < deg; e++){
    int s = row[e];
    if (lane < 40) a += hn[(size_t)s*40 + lane];
  }
  float val = (lane < 40) ? a*nd[v] : 0.f;
  agg[(size_t)v*64 + lane] = f2bf(val);
}

// ---------------- layers 2..4 prep: xs = relu(scale*x+shift)*ns, bf16 pairs ----------------
__global__ void k_prepH(const unsigned int* __restrict__ X, const float* __restrict__ ns,
                        const float* __restrict__ scale, const float* __restrict__ shift,
                        unsigned int* __restrict__ XS){
  int i = blockIdx.x*256 + threadIdx.x;
  if (i >= NN*64) return;
  int v = i >> 6;
  int c0 = (i & 63)*2;
  unsigned int u = X[i];
  float nsv = ns[v];
  float x0 = fmaxf(fmaf(lo2f(u), scale[c0],   shift[c0]),   0.f)*nsv;
  float x1 = fmaxf(fmaf(hi2f(u), scale[c0+1], shift[c0+1]), 0.f)*nsv;
  XS[i] = pack2(x0, x1);
}

// ---------------- layers 2..4 gather-sum over bf16 [N][128] rows, unroll 4 ----------------
__global__ __launch_bounds__(256)
void k_gs128(const unsigned short* __restrict__ xs, const int* __restrict__ eidx,
             const int* __restrict__ degI, const float* __restrict__ nd,
             unsigned short* __restrict__ agg){
  int v = (blockIdx.x*256 + threadIdx.x) >> 6;
  int lane = threadIdx.x & 63;
  if (v >= NN) return;
  int deg = degI[v]; if (deg > MAXDEG) deg = MAXDEG;
  const int* row = eidx + v*MAXDEG;
  int c = 2*lane;
  float a0 = 0.f, a1 = 0.f;
  int e = 0;
  for (; e+4 <= deg; e += 4){
    int4 s4 = *(const int4*)(row + e);
    unsigned int u0 = *(const unsigned int*)(xs + (size_t)s4.x*128 + c);
    unsigned int u1 = *(const unsigned int*)(xs + (size_t)s4.y*128 + c);
    unsigned int u2 = *(const unsigned int*)(xs + (size_t)s4.z*128 + c);
    unsigned int u3 = *(const unsigned int*)(xs + (size_t)s4.w*128 + c);
    a0 += lo2f(u0); a1 += hi2f(u0);
    a0 += lo2f(u1); a1 += hi2f(u1);
    a0 += lo2f(u2); a1 += hi2f(u2);
    a0 += lo2f(u3); a1 += hi2f(u3);
  }
  for (; e < deg; e++){
    int s = row[e];
    unsigned int u = *(const unsigned int*)(xs + (size_t)s*128 + c);
    a0 += lo2f(u); a1 += hi2f(u);
  }
  float ndv = nd[v];
  *(unsigned int*)(agg + (size_t)v*128 + c) = pack2(a0*ndv, a1*ndv);
}

// ---------------- MFMA GEMM (tile 128x128, 4 waves, BK=64), fused BN stats ----------------
__global__ __launch_bounds__(256)
void k_mgemm(const unsigned short* __restrict__ A, const unsigned short* __restrict__ Wt,
             const float* __restrict__ bias, unsigned short* __restrict__ Cout,
             float* __restrict__ stats, int M, int K, int Nc){
  __shared__ unsigned short As[128][72];
  __shared__ unsigned short Bs[128][72];
  __shared__ float sred[2][128];
  int m0 = blockIdx.x*128, n0 = blockIdx.y*128;
  int t = threadIdx.x, w = t>>6, lane = t&63;
  int wr = (w>>1)*64, wc = (w&1)*64;
  f32x4 acc[4][4] = {};

  int ar = t>>3;
  int ac = (t&7)*8;
  for (int k0=0; k0<K; k0+=64){
    #pragma unroll
    for (int rr=0; rr<128; rr+=32){
      int gm = m0 + ar + rr;
      bf16x8 val = {};
      if (gm < M) val = *(const bf16x8*)(A + (size_t)gm*K + k0 + ac);
      *(bf16x8*)&As[ar+rr][ac] = val;
    }
    #pragma unroll
    for (int rr=0; rr<128; rr+=32){
      int gc = n0 + ar + rr;
      bf16x8 val = {};
      if (gc < Nc) val = *(const bf16x8*)(Wt + (size_t)gc*K + k0 + ac);
      *(bf16x8*)&Bs[ar+rr][ac] = val;
    }
    __syncthreads();
    int rsel = lane & 15;
    #pragma unroll
    for (int kk=0; kk<64; kk+=32){
      int ksel = kk + (lane>>4)*8;
      bf16x8 af[4], bfr[4];
      #pragma unroll
      for (int i=0;i<4;i++) af[i]  = *(const bf16x8*)&As[wr + i*16 + rsel][ksel];
      #pragma unroll
      for (int j=0;j<4;j++) bfr[j] = *(const bf16x8*)&Bs[wc + j*16 + rsel][ksel];
      #pragma unroll
      for (int i=0;i<4;i++)
        #pragma unroll
        for (int j=0;j<4;j++)
          acc[i][j] = __builtin_amdgcn_mfma_f32_16x16x32_bf16(af[i], bfr[j], acc[i][j], 0, 0, 0);
    }
    __syncthreads();
  }

  float csum[4] = {}, csq[4] = {};
  int colsel = lane & 15, rowsel = (lane>>4)*4;
  #pragma unroll
  for (int j=0;j<4;j++){
    int gc = n0 + wc + j*16 + colsel;
    float bv = (gc < Nc) ? bias[gc] : 0.f;
    #pragma unroll
    for (int i=0;i<4;i++){
      #pragma unroll
      for (int r=0;r<4;r++){
        int gm = m0 + wr + i*16 + rowsel + r;
        if (gm < M && gc < Nc){
          float v = acc[i][j][r] + bv;
          Cout[(size_t)gm*Nc + gc] = f2bf(v);
          csum[j] += v; csq[j] += v*v;
        }
      }
    }
  }
  if (stats){
    ((float*)sred)[t] = 0.f;
    __syncthreads();
    #pragma unroll
    for (int j=0;j<4;j++){
      int lc = wc + j*16 + colsel;
      atomicAdd(&sred[0][lc], csum[j]);
      atomicAdd(&sred[1][lc], csq[j]);
    }
    __syncthreads();
    if (t < 128){
      int gc = n0 + t;
      if (gc < Nc){
        atomicAdd(&stats[gc],      sred[0][t]);
        atomicAdd(&stats[Nc + gc], sred[1][t]);
      }
    }
  }
}

// ---------------- BN finalize ----------------
__global__ void k_bnfin(const float* __restrict__ stats, const float* __restrict__ g,
                        const float* __restrict__ be, float invM, int C,
                        float* __restrict__ scale, float* __restrict__ shift){
  int c = blockIdx.x*blockDim.x + threadIdx.x;
  if (c < C){
    float m = stats[c]*invM;
    float var = fmaxf(stats[C+c]*invM - m*m, 0.f);
    float inv = rsqrtf(var + EPSB);
    float sc = g[c]*inv;
    scale[c] = sc;
    shift[c] = fmaf(-sc, m, be[c]);
  }
}

// ---------------- BN apply + ReLU on bf16 pairs (head only) ----------------
__global__ void k_bnapply_bf(const unsigned int* __restrict__ X, unsigned int* __restrict__ Y,
                             const float* __restrict__ scale, const float* __restrict__ shift,
                             size_t totalPairs, int pairMask){
  size_t i = (size_t)blockIdx.x*blockDim.x + threadIdx.x;
  size_t stride = (size_t)gridDim.x*blockDim.x;
  for (; i < totalPairs; i += stride){
    int c0 = 2*(int)(i & (size_t)pairMask);
    unsigned int u = X[i];
    float x0 = fmaxf(fmaf(lo2f(u), scale[c0],   shift[c0]),   0.f);
    float x1 = fmaxf(fmaf(hi2f(u), scale[c0+1], shift[c0+1]), 0.f);
    Y[i] = pack2(x0, x1);
  }
}

// ---------------- layer-4 activation + fused atom-weight dot ----------------
__global__ __launch_bounds__(256)
void k_prep4(const unsigned short* __restrict__ X, const float* __restrict__ scale,
             const float* __restrict__ shift, const float* __restrict__ aw,
             const float* __restrict__ ab, unsigned short* __restrict__ X4,
             float* __restrict__ awout, float* __restrict__ wsig){
  int v = (blockIdx.x*256 + threadIdx.x) >> 6;
  int lane = threadIdx.x & 63;
  if (v >= NN) return;
  int c0 = 2*lane;
  unsigned int u = *(const unsigned int*)(X + (size_t)v*128 + c0);
  float x0 = fmaxf(fmaf(lo2f(u), scale[c0],   shift[c0]),   0.f);
  float x1 = fmaxf(fmaf(hi2f(u), scale[c0+1], shift[c0+1]), 0.f);
  *(unsigned int*)(X4 + (size_t)v*128 + c0) = pack2(x0, x1);
  float s = x0*aw[c0] + x1*aw[c0+1];
  #pragma unroll
  for (int o=32;o>0;o>>=1) s += __shfl_xor(s, o);
  if (lane == 0){
    float tv = s + ab[0];
    awout[v] = tv;
    wsig[v] = sigmoidf_(tv);
  }
}

__global__ void k_bounds(const int* __restrict__ n2g, int* __restrict__ gs, int* __restrict__ ge){
  int v = blockIdx.x*256 + threadIdx.x;
  if (v < NN){
    int g = n2g[v];
    atomicMin(&gs[g], v);
    atomicMax(&ge[g], v+1);
  }
}

// ---------------- readout: one block (4 waves) per graph ----------------
__global__ __launch_bounds__(256)
void k_readout4(const unsigned short* __restrict__ X4, const float* __restrict__ wsig,
                const int* __restrict__ gs, const int* __restrict__ ge,
                unsigned short* __restrict__ hg){
  __shared__ float red[4][128];
  int g = blockIdx.x;
  int t = threadIdx.x, w = t>>6, lane = t&63;
  int s = gs[g], e = ge[g];
  int c0 = 2*lane;
  float a0=0.f, a1=0.f;
  for (int n = s + w; n < e; n += 4){
    float wn = wsig[n];
    unsigned int u = *(const unsigned int*)(X4 + (size_t)n*128 + c0);
    a0 = fmaf(lo2f(u), wn, a0);
    a1 = fmaf(hi2f(u), wn, a1);
  }
  red[w][c0] = a0; red[w][c0+1] = a1;
  __syncthreads();
  if (w == 0){
    a0 = red[0][c0] + red[1][c0] + red[2][c0] + red[3][c0];
    a1 = red[0][c0+1] + red[1][c0+1] + red[2][c0+1] + red[3][c0+1];
    *(unsigned int*)(hg + (size_t)g*128 + c0) = pack2(a0, a1);
  }
}

// ---------------- final small GEMM + sigmoid ----------------
__global__ void k_final(const unsigned short* __restrict__ y2, const float* __restrict__ Wf2,
                        const float* __restrict__ bf2v, float* __restrict__ out){
  int idx = blockIdx.x*256 + threadIdx.x;
  if (idx >= NG*67) return;
  int g = idx / 67, c = idx % 67;
  float s = bf2v[c];
  const unsigned short* row = y2 + (size_t)g*256;
  for (int k=0;k<256;k+=2){
    unsigned int u = *(const unsigned int*)(row + k);
    s = fmaf(lo2f(u), Wf2[(size_t)k*67 + c], s);
    s = fmaf(hi2f(u), Wf2[(size_t)(k+1)*67 + c], s);
  }
  out[(size_t)g*67 + c] = sigmoidf_(s);
}

extern "C" void kernel_launch(void* const* d_in, const int* in_sizes, int n_in,
                              void* d_out, int out_size, void* d_ws, size_t ws_size,
                              hipStream_t stream){
  const float* h   = (const float*)d_in[0];
  const int*   src = (const int*)d_in[1];
  const int*   dst = (const int*)d_in[2];
  const int*   n2g = (const int*)d_in[3];
  const float* W1  = (const float*)d_in[4];
  const float* b1  = (const float*)d_in[5];
  const float* g1  = (const float*)d_in[6];
  const float* be1 = (const float*)d_in[7];
  const float* W2s = (const float*)d_in[8];
  const float* b2s = (const float*)d_in[9];
  const float* g2s = (const float*)d_in[10];
  const float* be2s= (const float*)d_in[11];
  const float* aw  = (const float*)d_in[12];
  const float* ab  = (const float*)d_in[13];
  const float* Wf1 = (const float*)d_in[14];
  const float* bf1 = (const float*)d_in[15];
  const float* gf1 = (const float*)d_in[16];
  const float* bef1= (const float*)d_in[17];
  const float* Wl  = (const float*)d_in[18];
  const float* bl  = (const float*)d_in[19];
  const float* gl  = (const float*)d_in[20];
  const float* bel = (const float*)d_in[21];
  const float* Wf2 = (const float*)d_in[22];
  const float* bf2v= (const float*)d_in[23];
  float* out = (float*)d_out;

  char* p = (char*)d_ws;
  auto carve = [&](size_t bytes)->void*{
    void* r = (void*)p; p += (bytes + 255) & ~(size_t)255; return r;
  };
  unsigned short* X    = (unsigned short*)carve((size_t)NN*128*2);   // GEMM out (pre-BN)
  unsigned short* XS   = (unsigned short*)carve((size_t)NN*128*2);   // scaled gather src; X4 aliases
  unsigned short* AGG  = (unsigned short*)carve((size_t)NN*128*2);   // gather out; hn aliases
  unsigned short* A38  = (unsigned short*)carve((size_t)NN*64*2);    // layer-1 GEMM input
  int*   eidx = (int*)carve((size_t)NN*MAXDEG*4);
  int*   degO = (int*)carve((size_t)NN*4);
  int*   cnt  = (int*)carve((size_t)NN*4);                           // doubles as degI
  float* ns   = (float*)carve((size_t)NN*4);
  float* nd   = (float*)carve((size_t)NN*4);
  float* wsig = (float*)carve((size_t)NN*4);
  int*   gs   = (int*)carve((size_t)NG*4);
  int*   ge   = (int*)carve((size_t)NG*4);
  unsigned short* hg  = (unsigned short*)carve((size_t)NG*128*2);
  unsigned short* y1p = (unsigned short*)carve((size_t)NG*512*2);
  unsigned short* y1  = (unsigned short*)carve((size_t)NG*512*2);
  unsigned short* y2p = (unsigned short*)carve((size_t)NG*256*2);
  unsigned short* y2  = (unsigned short*)carve((size_t)NG*256*2);
  float* stats= (float*)carve(4096*4);
  float* scale= (float*)carve(512*4);
  float* shift= (float*)carve(512*4);
  unsigned short* W1t  = (unsigned short*)carve((size_t)128*64*2);
  unsigned short* W2t  = (unsigned short*)carve((size_t)3*128*128*2);
  unsigned short* Wf1t = (unsigned short*)carve((size_t)512*128*2);
  unsigned short* Wlt  = (unsigned short*)carve((size_t)256*512*2);

  float* hn = (float*)AGG;            // fp32 [NN][40] = 16MB ⊂ AGG (dead before AGG written)
  unsigned short* X4 = XS;            // layer-4 activations (XS dead by then)

  float* st1  = stats;
  float* st2a = stats + 256;
  float* st2b = stats + 512;
  float* st2c = stats + 768;
  float* stf1 = stats + 1024;
  float* stl  = stats + 2048;
  float* st2[3] = { st2a, st2b, st2c };

  hipMemsetAsync(degO, 0, (size_t)NN*4, stream);
  hipMemsetAsync(cnt,  0, (size_t)NN*4, stream);
  hipMemsetAsync(stats,0, (size_t)4096*4, stream);
  hipMemsetAsync(gs, 0x7F, (size_t)NG*4, stream);
  hipMemsetAsync(ge, 0,    (size_t)NG*4, stream);

  // weight conversion (independent)
  k_convW<<<(128*64+255)/256, 256, 0, stream>>>(W1, W1t, 38, 128, 64);
  for (int i=0;i<3;i++)
    k_convW<<<(128*128+255)/256, 256, 0, stream>>>(W2s + (size_t)i*128*128, W2t + (size_t)i*128*128, 128, 128, 128);
  k_convW<<<(512*128+255)/256, 256, 0, stream>>>(Wf1, Wf1t, 128, 512, 128);
  k_convW<<<(256*512+255)/256, 256, 0, stream>>>(Wl, Wlt, 512, 256, 512);

  // graph prep
  k_fillall<<<(NE+255)/256, 256, 0, stream>>>(src, dst, degO, cnt, eidx);
  k_norms  <<<(NN+255)/256, 256, 0, stream>>>(degO, cnt, ns, nd);

  const int nodeBlocks = (NN + 3)/4;
  const int gemmBlocks = (NN + 127)/128;

  // layer 1
  k_prep1<<<(NN*40+255)/256, 256, 0, stream>>>(h, ns, hn);
  k_gs40 <<<nodeBlocks, 256, 0, stream>>>(hn, eidx, cnt, nd, A38);
  k_mgemm<<<dim3(gemmBlocks,1), 256, 0, stream>>>(A38, W1t, b1, X, st1, NN, 64, 128);
  k_bnfin<<<1, 128, 0, stream>>>(st1, g1, be1, 1.0f/(float)NN, 128, scale, shift);

  // layers 2..4
  for (int i=0;i<3;i++){
    k_prepH<<<(NN*64+255)/256, 256, 0, stream>>>((const unsigned int*)X, ns, scale, shift,
                                                 (unsigned int*)XS);
    k_gs128<<<nodeBlocks, 256, 0, stream>>>(XS, eidx, cnt, nd, AGG);
    k_mgemm<<<dim3(gemmBlocks,1), 256, 0, stream>>>(AGG, W2t + (size_t)i*128*128, b2s + i*128,
                                                    X, st2[i], NN, 128, 128);
    k_bnfin<<<1, 128, 0, stream>>>(st2[i], g2s + i*128, be2s + i*128, 1.0f/(float)NN, 128, scale, shift);
  }

  // layer-4 activation + atom weights
  k_prep4<<<nodeBlocks, 256, 0, stream>>>(X, scale, shift, aw, ab, X4,
                                          out + (size_t)NG*67, wsig);
  k_bounds<<<(NN+255)/256, 256, 0, stream>>>(n2g, gs, ge);
  k_readout4<<<NG, 256, 0, stream>>>(X4, wsig, gs, ge, hg);

  // head
  k_mgemm<<<dim3(NG/128, 4), 256, 0, stream>>>(hg, Wf1t, bf1, y1p, stf1, NG, 128, 512);
  k_bnfin<<<1, 512, 0, stream>>>(stf1, gf1, bef1, 1.0f/(float)NG, 512, scale, shift);
  k_bnapply_bf<<<512, 256, 0, stream>>>((const unsigned int*)y1p, (unsigned int*)y1,
                                        scale, shift, (size_t)NG*256, 255);

  k_mgemm<<<dim3(NG/128, 2), 256, 0, stream>>>(y1, Wlt, bl, y2p, stl, NG, 512, 256);
  k_bnfin<<<1, 256, 0, stream>>>(stl, gl, bel, 1.0f/(float)NG, 256, scale, shift);
  k_bnapply_bf<<<256, 256, 0, stream>>>((const unsigned int*)y2p, (unsigned int*)y2,
                                        scale, shift, (size_t)NG*128, 127);

  k_final<<<(NG*67+255)/256, 256, 0, stream>>>(y2, Wf2, bf2v, out);
}